// Round 5
// baseline (141.600 us; speedup 1.0000x reference)
//
#include <hip/hip_runtime.h>

// Problem constants (from reference setup_inputs)
#define B_   32
#define T_   4096
#define D_   128
#define TU   512
#define M_   8
#define O_   64      // Dout
#define BN_EPS 1e-5f

// 16 B vector with 4 B alignment: feat windows start at +1 float within the
// 516 B row, so only element-aligned; gfx950 handles line straddle in HW.
typedef float f4u __attribute__((ext_vector_type(4), aligned(4)));

// ws (int) layout: CSR structures, ~1.2 MB total (well under proven 8 MB)
#define WS_UIDX   0                       // [B_*T_]  per-row bin or -1
#define WS_BASE   (B_ * T_)               // [B_*TU]  bin start offset (per b)
#define WS_END    (WS_BASE + B_ * TU)     // [B_*TU]  bin end offset
#define WS_ROWIDX (WS_END + B_ * TU)      // [B_*T_]  row ids grouped by bin

// ---------------------------------------------------------------------------
// R4 gather redesign. R3 PMC (VALU 5%, HBM 17%, conflicts 0): scatter phase was
// line-fetch limited (16B@516B stride = 25% line util). R4's t-partition was
// mathematically wrong (sum of partial maxes). Fix: INVERT scatter -> gather.
//   K1 index:  uidx[b,t] = mask ? clamp(tw - u0) : -1
//   K2 build:  per-b count + scan + fill -> CSR (base/end/rowidx)
//   K3 gather: per bin u: half-wave loads each member row as ONE contiguous
//              512 B read, max-reduce in REGISTERS (no atomics, no barriers,
//              no cross-block merge), fold BN+conv+fc, write out directly.
// ---------------------------------------------------------------------------

__global__ __launch_bounds__(256) void index_kernel(
    const float* __restrict__ x, const int* __restrict__ mask,
    const float* __restrict__ tw_uniq, int* __restrict__ wsI) {
    const int g = blockIdx.x * 256 + threadIdx.x;   // 0..131071 = b*T_+t
    const int b = g >> 12;
    const float twf = x[(size_t)g * (D_ + 1)];      // row word 0 = tw
    const int   mk  = mask[g];
    const float u0  = tw_uniq[b * TU];
    const int   u   = min(max((int)(twf - u0), 0), TU - 1);
    wsI[WS_UIDX + g] = mk ? u : -1;
}

// one block per b: LDS count (atomics) -> Hillis-Steele scan -> fill rowidx
__global__ __launch_bounds__(1024) void build_kernel(int* __restrict__ wsI) {
    __shared__ int cnt[TU];
    __shared__ int scn[TU];
    __shared__ int cur[TU];
    const int b = blockIdx.x;
    const int tid = threadIdx.x;
    if (tid < TU) cnt[tid] = 0;
    __syncthreads();
    const int* ub = wsI + WS_UIDX + b * T_;
    int uv[4];
#pragma unroll
    for (int r = 0; r < 4; ++r) {
        uv[r] = ub[r * 1024 + tid];
        if (uv[r] >= 0) atomicAdd(&cnt[uv[r]], 1);
    }
    __syncthreads();
    if (tid < TU) scn[tid] = cnt[tid];
    __syncthreads();
    for (int off = 1; off < TU; off <<= 1) {       // inclusive scan
        int v = 0;
        if (tid < TU && tid >= off) v = scn[tid - off];
        __syncthreads();
        if (tid < TU) scn[tid] += v;
        __syncthreads();
    }
    if (tid < TU) {
        const int e = scn[tid];
        const int s = e - cnt[tid];                // exclusive base
        wsI[WS_BASE + b * TU + tid] = s;
        wsI[WS_END  + b * TU + tid] = e;
        cur[tid] = s;
    }
    __syncthreads();
    int* rb = wsI + WS_ROWIDX + b * T_;
#pragma unroll
    for (int r = 0; r < 4; ++r) {
        if (uv[r] >= 0) {
            const int pos = atomicAdd(&cur[uv[r]], 1);
            rb[pos] = r * 1024 + tid;              // order in bin irrelevant (max)
        }
    }
}

// grid 256 = (b x 8 u-chunks of 64), 1024 thr = 16 waves x 4 bins each.
// XCD swizzle: all 8 u-chunk blocks of batch b share one XCD (L2 dedup of
// row-boundary lines): b = (j&7) + 8*((j>>3)&3), uc = j>>5.
__global__ __launch_bounds__(1024) void gather_mm_kernel(
    const float* __restrict__ x,
    const float* __restrict__ bn_gamma, const float* __restrict__ bn_beta,
    const float* __restrict__ bn_mean,  const float* __restrict__ bn_var,
    const float* __restrict__ conv_w,   const float* __restrict__ conv_b,
    const float* __restrict__ fc_w,     const float* __restrict__ fc_b,
    const int* __restrict__ wsI, float* __restrict__ out) {
    __shared__ float wsm[M_ * D_];   // folded weights Weff[m][d], 4 KB
    __shared__ float tmp[M_ * D_];
    __shared__ float biasc[M_];
    const int j = blockIdx.x;
    const int b  = (j & 7) + 8 * ((j >> 3) & 3);
    const int uc = j >> 5;                          // 0..7
    const int tid = threadIdx.x;

    // ---- fold BN+conv+fc: tid = m*128 + d (exactly 1024 threads) ----
    {
        const int m = tid >> 7, d = tid & (D_ - 1);
        float wraw = 0.f;
        for (int o = 0; o < O_; ++o) wraw += fc_w[m * O_ + o] * conv_w[o * D_ + d];
        const float sc = bn_gamma[d] * rsqrtf(bn_var[d] + BN_EPS);
        const float sh = bn_beta[d] - bn_mean[d] * sc;
        wsm[tid] = wraw * sc;
        tmp[tid] = wraw * sh;
    }
    __syncthreads();
    if (tid < M_) {
        float s = fc_b[tid];
        for (int o = 0; o < O_; ++o) s += fc_w[tid * O_ + o] * conv_b[o];
        for (int d = 0; d < D_; ++d) s += tmp[tid * D_ + d];
        biasc[tid] = s;
    }
    __syncthreads();

    const int w    = tid >> 6;        // wave 0..15
    const int lane = tid & 63;
    const int half = lane >> 5;       // two rows in flight per wave
    const int lq   = lane & 31;       // d-quad: d = lq*4 .. +3 (contiguous 512 B/row)
    const float* xb = x + (size_t)b * T_ * (D_ + 1);
    const int* rowb = wsI + WS_ROWIDX + b * T_;

    for (int k = 0; k < 4; ++k) {
        const int u = uc * 64 + w * 4 + k;
        const int start = wsI[WS_BASE + b * TU + u];
        const int end   = wsI[WS_END  + b * TU + u];
        float a0 = 0.f, a1 = 0.f, a2 = 0.f, a3 = 0.f;   // hidden init = 0
        int  r    = start + half;
        bool have = r < end;
        f4u  vn;
        if (have) { vn = *(const f4u*)(xb + (size_t)rowb[r] * (D_ + 1) + 1 + lq * 4); r += 2; }
        while (have) {                                   // 1-deep prefetch pipeline
            const f4u v = vn;
            have = r < end;
            if (have) { vn = *(const f4u*)(xb + (size_t)rowb[r] * (D_ + 1) + 1 + lq * 4); r += 2; }
            a0 = fmaxf(a0, v.x); a1 = fmaxf(a1, v.y);
            a2 = fmaxf(a2, v.z); a3 = fmaxf(a3, v.w);
        }
        // merge the two half-wave row streams (lanes l and l+32 share d-quad)
        a0 = fmaxf(a0, __shfl_xor(a0, 32)); a1 = fmaxf(a1, __shfl_xor(a1, 32));
        a2 = fmaxf(a2, __shfl_xor(a2, 32)); a3 = fmaxf(a3, __shfl_xor(a3, 32));

        // partial dots: this lane owns d = lq*4..lq*4+3
        const int db = lq * 4;
        float p0, p1, p2, p3, p4, p5, p6, p7;
#define PDOT(mm) (a0 * wsm[(mm) * D_ + db] + a1 * wsm[(mm) * D_ + db + 1] + \
                  a2 * wsm[(mm) * D_ + db + 2] + a3 * wsm[(mm) * D_ + db + 3])
        p0 = PDOT(0); p1 = PDOT(1); p2 = PDOT(2); p3 = PDOT(3);
        p4 = PDOT(4); p5 = PDOT(5); p6 = PDOT(6); p7 = PDOT(7);
#undef PDOT
        // reduce over the 32 lanes of each half (halves identical after merge)
#pragma unroll
        for (int off = 1; off < 32; off <<= 1) {
            p0 += __shfl_xor(p0, off); p1 += __shfl_xor(p1, off);
            p2 += __shfl_xor(p2, off); p3 += __shfl_xor(p3, off);
            p4 += __shfl_xor(p4, off); p5 += __shfl_xor(p5, off);
            p6 += __shfl_xor(p6, off); p7 += __shfl_xor(p7, off);
        }
        if (lane == 0) {
            float* op = out + ((size_t)(b * TU + u)) * M_;
            *(float4*)(op)     = make_float4(p0 + biasc[0], p1 + biasc[1],
                                             p2 + biasc[2], p3 + biasc[3]);
            *(float4*)(op + 4) = make_float4(p4 + biasc[4], p5 + biasc[5],
                                             p6 + biasc[6], p7 + biasc[7]);
        }
    }
}

extern "C" void kernel_launch(void* const* d_in, const int* in_sizes, int n_in,
                              void* d_out, int out_size, void* d_ws, size_t ws_size,
                              hipStream_t stream) {
    const float* x        = (const float*)d_in[0];   // (32,4096,129) f32
    const int*   mask     = (const int*)  d_in[1];   // (32,4096,1) bool->int32
    const float* tw_uniq  = (const float*)d_in[2];   // (32,512,1) f32
    const float* bn_gamma = (const float*)d_in[3];
    const float* bn_beta  = (const float*)d_in[4];
    const float* bn_mean  = (const float*)d_in[5];
    const float* bn_var   = (const float*)d_in[6];
    const float* conv_w   = (const float*)d_in[7];   // (64,128)
    const float* conv_b   = (const float*)d_in[8];   // (64,)
    const float* fc_w     = (const float*)d_in[9];   // (8,64)
    const float* fc_b     = (const float*)d_in[10];  // (8,)
    int*   wsI = (int*)d_ws;                         // ~1.2 MB CSR
    float* out = (float*)d_out;                      // (32,512,8) f32

    index_kernel<<<512, 256, 0, stream>>>(x, mask, tw_uniq, wsI);
    build_kernel<<<32, 1024, 0, stream>>>(wsI);
    gather_mm_kernel<<<256, 1024, 0, stream>>>(
        x, bn_gamma, bn_beta, bn_mean, bn_var,
        conv_w, conv_b, fc_w, fc_b, wsI, out);
}

// Round 6
// 136.952 us; speedup vs baseline: 1.0339x; 1.0339x over previous
//
#include <hip/hip_runtime.h>

// Problem constants (from reference setup_inputs)
#define B_   32
#define T_   4096
#define D_   128
#define TU   512
#define M_   8
#define O_   64      // Dout
#define BN_EPS 1e-5f

// 16 B vector with 4 B alignment: feat windows start at +1 float within the
// 516 B row, so only element-aligned; gfx950 handles line straddle in HW.
typedef float f4u __attribute__((ext_vector_type(4), aligned(4)));

// ws (int) layout: CSR structures, ~655 KB
#define WS_BASE   0                       // [B_*TU]  bin start offset (per b)
#define WS_END    (B_ * TU)               // [B_*TU]  bin end offset
#define WS_ROWIDX (2 * B_ * TU)           // [B_*T_]  row ids grouped by bin

// ---------------------------------------------------------------------------
// R6: R5 PMC (gather_mm 40.8us, 845 GB/s, VALU 11%, occ 29%) = latency-bound:
// each row cost TWO chained VMEM latencies (rowb[r] -> row) at 1-deep
// prefetch, bins drained sequentially. Fix: (a) bulk bin-index load into
// lanes + register __shfl broadcast (kills the index chain), (b) 8-deep
// static-reg load bursts (outstanding bytes/CU ~100x), (c) one bin per
// half-wave (no merge), grid 512.
//   K1 build:  fused index+CSR: uidx in LDS, count -> scan -> fill rowidx
//   K2 gather: per bin u: half-wave bursts member rows (contiguous 512 B
//              each), max-reduces in REGISTERS, folds BN+conv+fc, writes out.
// ---------------------------------------------------------------------------

// one block per b: compute uidx in LDS, LDS count -> Hillis-Steele scan -> fill
__global__ __launch_bounds__(1024) void build_kernel(
    const float* __restrict__ x, const int* __restrict__ mask,
    const float* __restrict__ tw_uniq, int* __restrict__ wsI) {
    __shared__ int uloc[T_];     // 16 KB
    __shared__ int cnt[TU];
    __shared__ int scn[TU];
    __shared__ int cur[TU];
    const int b = blockIdx.x;
    const int tid = threadIdx.x;
    if (tid < TU) cnt[tid] = 0;
    __syncthreads();
    const float* xb = x + (size_t)b * T_ * (D_ + 1);
    const int*   mb = mask + b * T_;
    const float  u0 = tw_uniq[b * TU];
#pragma unroll
    for (int r = 0; r < 4; ++r) {
        const int t = r * 1024 + tid;
        const float twf = xb[(size_t)t * (D_ + 1)];   // row word 0 = tw
        const int   mk  = mb[t];
        const int   u   = min(max((int)(twf - u0), 0), TU - 1);
        uloc[t] = mk ? u : -1;
        if (mk) atomicAdd(&cnt[u], 1);
    }
    __syncthreads();
    if (tid < TU) scn[tid] = cnt[tid];
    __syncthreads();
    for (int off = 1; off < TU; off <<= 1) {       // inclusive scan
        int v = 0;
        if (tid < TU && tid >= off) v = scn[tid - off];
        __syncthreads();
        if (tid < TU) scn[tid] += v;
        __syncthreads();
    }
    if (tid < TU) {
        const int e = scn[tid];
        const int s = e - cnt[tid];                // exclusive base
        wsI[WS_BASE + b * TU + tid] = s;
        wsI[WS_END  + b * TU + tid] = e;
        cur[tid] = s;
    }
    __syncthreads();
    int* rb = wsI + WS_ROWIDX + b * T_;
#pragma unroll
    for (int r = 0; r < 4; ++r) {
        const int t = r * 1024 + tid;
        const int u = uloc[t];
        if (u >= 0) {
            const int pos = atomicAdd(&cur[u], 1);
            rb[pos] = t;                           // order in bin irrelevant (max)
        }
    }
}

// grid 512 = (b x 16 u-chunks of 32), 1024 thr = 16 waves; ONE bin per
// half-wave. XCD swizzle: all 16 u-chunk blocks of batch b share one XCD:
//   b = (j&7) + 8*((j>>3)&3), uc = j>>5 (0..15).
__global__ __launch_bounds__(1024, 4) void gather_mm_kernel(
    const float* __restrict__ x,
    const float* __restrict__ bn_gamma, const float* __restrict__ bn_beta,
    const float* __restrict__ bn_mean,  const float* __restrict__ bn_var,
    const float* __restrict__ conv_w,   const float* __restrict__ conv_b,
    const float* __restrict__ fc_w,     const float* __restrict__ fc_b,
    const int* __restrict__ wsI, float* __restrict__ out) {
    __shared__ float wsm[M_ * D_];   // folded weights Weff[m][d], 4 KB
    __shared__ float tmp[M_ * D_];
    __shared__ float biasc[M_];
    const int j = blockIdx.x;
    const int b  = (j & 7) + 8 * ((j >> 3) & 3);
    const int uc = j >> 5;                          // 0..15
    const int tid = threadIdx.x;

    // ---- fold BN+conv+fc: tid = m*128 + d (exactly 1024 threads) ----
    {
        const int m = tid >> 7, d = tid & (D_ - 1);
        float wraw = 0.f;
        for (int o = 0; o < O_; ++o) wraw += fc_w[m * O_ + o] * conv_w[o * D_ + d];
        const float sc = bn_gamma[d] * rsqrtf(bn_var[d] + BN_EPS);
        const float sh = bn_beta[d] - bn_mean[d] * sc;
        wsm[tid] = wraw * sc;
        tmp[tid] = wraw * sh;
    }
    __syncthreads();
    if (tid < M_) {
        float s = fc_b[tid];
        for (int o = 0; o < O_; ++o) s += fc_w[tid * O_ + o] * conv_b[o];
        for (int d = 0; d < D_; ++d) s += tmp[tid * D_ + d];
        biasc[tid] = s;
    }
    __syncthreads();

    const int w    = tid >> 6;        // wave 0..15
    const int lane = tid & 63;
    const int half = lane >> 5;       // bin selector within wave
    const int lq   = lane & 31;       // d-quad: d = lq*4 .. +3 (512 B/row)
    const float* xb = x + (size_t)b * T_ * (D_ + 1);
    const int* rowb = wsI + WS_ROWIDX + b * T_;

    const int u     = uc * 32 + w * 2 + half;
    const int start = wsI[WS_BASE + b * TU + u];
    const int end   = wsI[WS_END  + b * TU + u];
    const int n     = end - start;
    const int nn    = min(n, 32);
    // bulk index load: lane lq holds index of bin-row lq (one load per bin)
    int myidx = 0;
    if (lq < n) myidx = rowb[start + lq];

    float a0 = 0.f, a1 = 0.f, a2 = 0.f, a3 = 0.f;   // hidden init = 0
#define ROWP(i) (const f4u*)(xb + (size_t)__shfl(myidx, (half << 5) + (i)) * (D_ + 1) + 1 + (lq << 2))
    for (int bs = 0; bs < nn; bs += 8) {             // 8-deep load bursts
        const int m = nn - bs;
        f4u t0, t1, t2, t3, t4, t5, t6, t7;
        if (m > 0) t0 = *ROWP(bs + 0);
        if (m > 1) t1 = *ROWP(bs + 1);
        if (m > 2) t2 = *ROWP(bs + 2);
        if (m > 3) t3 = *ROWP(bs + 3);
        if (m > 4) t4 = *ROWP(bs + 4);
        if (m > 5) t5 = *ROWP(bs + 5);
        if (m > 6) t6 = *ROWP(bs + 6);
        if (m > 7) t7 = *ROWP(bs + 7);
        if (m > 0) { a0 = fmaxf(a0, t0.x); a1 = fmaxf(a1, t0.y); a2 = fmaxf(a2, t0.z); a3 = fmaxf(a3, t0.w); }
        if (m > 1) { a0 = fmaxf(a0, t1.x); a1 = fmaxf(a1, t1.y); a2 = fmaxf(a2, t1.z); a3 = fmaxf(a3, t1.w); }
        if (m > 2) { a0 = fmaxf(a0, t2.x); a1 = fmaxf(a1, t2.y); a2 = fmaxf(a2, t2.z); a3 = fmaxf(a3, t2.w); }
        if (m > 3) { a0 = fmaxf(a0, t3.x); a1 = fmaxf(a1, t3.y); a2 = fmaxf(a2, t3.z); a3 = fmaxf(a3, t3.w); }
        if (m > 4) { a0 = fmaxf(a0, t4.x); a1 = fmaxf(a1, t4.y); a2 = fmaxf(a2, t4.z); a3 = fmaxf(a3, t4.w); }
        if (m > 5) { a0 = fmaxf(a0, t5.x); a1 = fmaxf(a1, t5.y); a2 = fmaxf(a2, t5.z); a3 = fmaxf(a3, t5.w); }
        if (m > 6) { a0 = fmaxf(a0, t6.x); a1 = fmaxf(a1, t6.y); a2 = fmaxf(a2, t6.z); a3 = fmaxf(a3, t6.w); }
        if (m > 7) { a0 = fmaxf(a0, t7.x); a1 = fmaxf(a1, t7.y); a2 = fmaxf(a2, t7.z); a3 = fmaxf(a3, t7.w); }
    }
#undef ROWP
    // rare big-bin (n > 32) remainder: sequential, uniform per half-wave
    for (int r = start + 32; r < end; ++r) {
        const f4u v = *(const f4u*)(xb + (size_t)rowb[r] * (D_ + 1) + 1 + (lq << 2));
        a0 = fmaxf(a0, v.x); a1 = fmaxf(a1, v.y);
        a2 = fmaxf(a2, v.z); a3 = fmaxf(a3, v.w);
    }

    // partial dots: this lane owns d = lq*4..lq*4+3
    const int db = lq << 2;
    float p0, p1, p2, p3, p4, p5, p6, p7;
#define PDOT(mm) (a0 * wsm[(mm) * D_ + db] + a1 * wsm[(mm) * D_ + db + 1] + \
                  a2 * wsm[(mm) * D_ + db + 2] + a3 * wsm[(mm) * D_ + db + 3])
    p0 = PDOT(0); p1 = PDOT(1); p2 = PDOT(2); p3 = PDOT(3);
    p4 = PDOT(4); p5 = PDOT(5); p6 = PDOT(6); p7 = PDOT(7);
#undef PDOT
    // reduce across the 32 lanes of this half (xor offsets < 32 stay in-half)
#pragma unroll
    for (int off = 1; off < 32; off <<= 1) {
        p0 += __shfl_xor(p0, off); p1 += __shfl_xor(p1, off);
        p2 += __shfl_xor(p2, off); p3 += __shfl_xor(p3, off);
        p4 += __shfl_xor(p4, off); p5 += __shfl_xor(p5, off);
        p6 += __shfl_xor(p6, off); p7 += __shfl_xor(p7, off);
    }
    if (lq == 0) {                    // lane 0 and lane 32 write their bins
        float* op = out + ((size_t)(b * TU + u)) * M_;
        *(float4*)(op)     = make_float4(p0 + biasc[0], p1 + biasc[1],
                                         p2 + biasc[2], p3 + biasc[3]);
        *(float4*)(op + 4) = make_float4(p4 + biasc[4], p5 + biasc[5],
                                         p6 + biasc[6], p7 + biasc[7]);
    }
}

extern "C" void kernel_launch(void* const* d_in, const int* in_sizes, int n_in,
                              void* d_out, int out_size, void* d_ws, size_t ws_size,
                              hipStream_t stream) {
    const float* x        = (const float*)d_in[0];   // (32,4096,129) f32
    const int*   mask     = (const int*)  d_in[1];   // (32,4096,1) bool->int32
    const float* tw_uniq  = (const float*)d_in[2];   // (32,512,1) f32
    const float* bn_gamma = (const float*)d_in[3];
    const float* bn_beta  = (const float*)d_in[4];
    const float* bn_mean  = (const float*)d_in[5];
    const float* bn_var   = (const float*)d_in[6];
    const float* conv_w   = (const float*)d_in[7];   // (64,128)
    const float* conv_b   = (const float*)d_in[8];   // (64,)
    const float* fc_w     = (const float*)d_in[9];   // (8,64)
    const float* fc_b     = (const float*)d_in[10];  // (8,)
    int*   wsI = (int*)d_ws;                         // ~655 KB CSR
    float* out = (float*)d_out;                      // (32,512,8) f32

    build_kernel<<<32, 1024, 0, stream>>>(x, mask, tw_uniq, wsI);
    gather_mm_kernel<<<512, 1024, 0, stream>>>(
        x, bn_gamma, bn_beta, bn_mean, bn_var,
        conv_w, conv_b, fc_w, fc_b, wsI, out);
}

// Round 7
// 130.405 us; speedup vs baseline: 1.0859x; 1.0502x over previous
//
#include <hip/hip_runtime.h>

// Problem constants (from reference setup_inputs)
#define B_   32
#define T_   4096
#define D_   128
#define TU   512
#define M_   8
#define O_   64      // Dout
#define CAP  64      // fixed bin capacity (mean 7.2, sigma 2.7 -> 21 sigma)
#define BN_EPS 1e-5f

// 16 B vector with 4 B alignment: feat windows start at +1 float within the
// 516 B row, so only element-aligned; gfx950 handles line straddle in HW.
typedef float f4u __attribute__((ext_vector_type(4), aligned(4)));

// ws (int) layout: cnt[B_*TU] then rowidx[B_*TU][CAP]  (~4.06 MB total)
#define WS_CNT 0
#define WS_ROW (B_ * TU)

// ---------------------------------------------------------------------------
// R7: R6 budget arithmetic (headline 136.9 = 82 fill-tax + ~55 us ours) says
// build_kernel (32 blocks = 1/8 machine, 18-barrier scan, 262 KB strided
// fetch/CU) dominates. The scan only exists to COMPACT bins -- unnecessary.
//   memset:  zero cnt (64 KB, stream-ordered)
//   K1 fill: one row/thread over 256 blocks: u = clamp(tw-u0); pos =
//            atomicAdd(cnt[b,u]); rb[(b,u)*CAP+pos] = t.  No scan.
//   K2 gather: per bin u: half-wave bulk-loads bin indices into lanes
//            (register __shfl broadcast), 8-deep 512 B row bursts,
//            max-reduce in REGISTERS, fold BN+conv+fc, write out.
// ---------------------------------------------------------------------------

__global__ __launch_bounds__(512) void fill_kernel(
    const float* __restrict__ x, const int* __restrict__ mask,
    const float* __restrict__ tw_uniq, int* __restrict__ wsI) {
    const int g = blockIdx.x * 512 + threadIdx.x;   // 0..131071 = b*T_+t
    const int b = g >> 12;
    const int t = g & (T_ - 1);
    const float twf = x[(size_t)g * (D_ + 1)];      // row word 0 = tw
    if (mask[g] == 0) return;
    const float u0 = tw_uniq[b * TU];
    const int   u  = min(max((int)(twf - u0), 0), TU - 1);
    const int  bin = b * TU + u;
    const int  pos = atomicAdd(&wsI[WS_CNT + bin], 1);   // device-scope
    if (pos < CAP) wsI[WS_ROW + bin * CAP + pos] = t;    // order irrelevant (max)
}

// grid 512 = (b x 16 u-chunks of 32), 1024 thr = 16 waves; ONE bin per
// half-wave; 2 blocks/CU via __launch_bounds__(1024,8) (VGPR<=64, LDS 8KB).
// XCD swizzle: all 16 u-chunk blocks of batch b share one XCD:
//   b = (j&7) + 8*((j>>3)&3), uc = j>>5 (0..15).
__global__ __launch_bounds__(1024, 8) void gather_mm_kernel(
    const float* __restrict__ x,
    const float* __restrict__ bn_gamma, const float* __restrict__ bn_beta,
    const float* __restrict__ bn_mean,  const float* __restrict__ bn_var,
    const float* __restrict__ conv_w,   const float* __restrict__ conv_b,
    const float* __restrict__ fc_w,     const float* __restrict__ fc_b,
    const int* __restrict__ wsI, float* __restrict__ out) {
    __shared__ float wsm[M_ * D_];   // folded weights Weff[m][d], 4 KB
    __shared__ float tmp[M_ * D_];
    __shared__ float biasc[M_];
    const int j = blockIdx.x;
    const int b  = (j & 7) + 8 * ((j >> 3) & 3);
    const int uc = j >> 5;                          // 0..15
    const int tid = threadIdx.x;

    // ---- fold BN+conv+fc: tid = m*128 + d (exactly 1024 threads) ----
    {
        const int m = tid >> 7, d = tid & (D_ - 1);
        float wraw = 0.f;
        for (int o = 0; o < O_; ++o) wraw += fc_w[m * O_ + o] * conv_w[o * D_ + d];
        const float sc = bn_gamma[d] * rsqrtf(bn_var[d] + BN_EPS);
        const float sh = bn_beta[d] - bn_mean[d] * sc;
        wsm[tid] = wraw * sc;
        tmp[tid] = wraw * sh;
    }
    __syncthreads();
    if (tid < M_) {
        float s = fc_b[tid];
        for (int o = 0; o < O_; ++o) s += fc_w[tid * O_ + o] * conv_b[o];
        for (int d = 0; d < D_; ++d) s += tmp[tid * D_ + d];
        biasc[tid] = s;
    }
    __syncthreads();

    const int w    = tid >> 6;        // wave 0..15
    const int lane = tid & 63;
    const int half = lane >> 5;       // bin selector within wave
    const int lq   = lane & 31;       // d-quad: d = lq*4 .. +3 (512 B/row)
    const float* xb = x + (size_t)b * T_ * (D_ + 1);

    const int u      = uc * 32 + w * 2 + half;
    const int bin    = b * TU + u;
    const int n      = min(wsI[WS_CNT + bin], CAP);
    const int* rowbin = wsI + WS_ROW + (size_t)bin * CAP;
    const int nn     = min(n, 32);
    // bulk index load: lane lq holds index of bin-row lq (one load per bin)
    int myidx = 0;
    if (lq < nn) myidx = rowbin[lq];

    float a0 = 0.f, a1 = 0.f, a2 = 0.f, a3 = 0.f;   // hidden init = 0
#define ROWP(i) (const f4u*)(xb + (size_t)__shfl(myidx, (half << 5) + (i)) * (D_ + 1) + 1 + (lq << 2))
    for (int bs = 0; bs < nn; bs += 8) {             // 8-deep load bursts
        const int m = nn - bs;
        f4u t0, t1, t2, t3, t4, t5, t6, t7;
        if (m > 0) t0 = *ROWP(bs + 0);
        if (m > 1) t1 = *ROWP(bs + 1);
        if (m > 2) t2 = *ROWP(bs + 2);
        if (m > 3) t3 = *ROWP(bs + 3);
        if (m > 4) t4 = *ROWP(bs + 4);
        if (m > 5) t5 = *ROWP(bs + 5);
        if (m > 6) t6 = *ROWP(bs + 6);
        if (m > 7) t7 = *ROWP(bs + 7);
        if (m > 0) { a0 = fmaxf(a0, t0.x); a1 = fmaxf(a1, t0.y); a2 = fmaxf(a2, t0.z); a3 = fmaxf(a3, t0.w); }
        if (m > 1) { a0 = fmaxf(a0, t1.x); a1 = fmaxf(a1, t1.y); a2 = fmaxf(a2, t1.z); a3 = fmaxf(a3, t1.w); }
        if (m > 2) { a0 = fmaxf(a0, t2.x); a1 = fmaxf(a1, t2.y); a2 = fmaxf(a2, t2.z); a3 = fmaxf(a3, t2.w); }
        if (m > 3) { a0 = fmaxf(a0, t3.x); a1 = fmaxf(a1, t3.y); a2 = fmaxf(a2, t3.z); a3 = fmaxf(a3, t3.w); }
        if (m > 4) { a0 = fmaxf(a0, t4.x); a1 = fmaxf(a1, t4.y); a2 = fmaxf(a2, t4.z); a3 = fmaxf(a3, t4.w); }
        if (m > 5) { a0 = fmaxf(a0, t5.x); a1 = fmaxf(a1, t5.y); a2 = fmaxf(a2, t5.z); a3 = fmaxf(a3, t5.w); }
        if (m > 6) { a0 = fmaxf(a0, t6.x); a1 = fmaxf(a1, t6.y); a2 = fmaxf(a2, t6.z); a3 = fmaxf(a3, t6.w); }
        if (m > 7) { a0 = fmaxf(a0, t7.x); a1 = fmaxf(a1, t7.y); a2 = fmaxf(a2, t7.z); a3 = fmaxf(a3, t7.w); }
    }
#undef ROWP
    // rare big-bin (n > 32) remainder: uniform per half-wave
    for (int i2 = 32; i2 < n; ++i2) {
        const f4u v = *(const f4u*)(xb + (size_t)rowbin[i2] * (D_ + 1) + 1 + (lq << 2));
        a0 = fmaxf(a0, v.x); a1 = fmaxf(a1, v.y);
        a2 = fmaxf(a2, v.z); a3 = fmaxf(a3, v.w);
    }

    // partial dots: this lane owns d = lq*4..lq*4+3
    const int db = lq << 2;
    float p0, p1, p2, p3, p4, p5, p6, p7;
#define PDOT(mm) (a0 * wsm[(mm) * D_ + db] + a1 * wsm[(mm) * D_ + db + 1] + \
                  a2 * wsm[(mm) * D_ + db + 2] + a3 * wsm[(mm) * D_ + db + 3])
    p0 = PDOT(0); p1 = PDOT(1); p2 = PDOT(2); p3 = PDOT(3);
    p4 = PDOT(4); p5 = PDOT(5); p6 = PDOT(6); p7 = PDOT(7);
#undef PDOT
    // reduce across the 32 lanes of this half (xor offsets < 32 stay in-half)
#pragma unroll
    for (int off = 1; off < 32; off <<= 1) {
        p0 += __shfl_xor(p0, off); p1 += __shfl_xor(p1, off);
        p2 += __shfl_xor(p2, off); p3 += __shfl_xor(p3, off);
        p4 += __shfl_xor(p4, off); p5 += __shfl_xor(p5, off);
        p6 += __shfl_xor(p6, off); p7 += __shfl_xor(p7, off);
    }
    if (lq == 0) {                    // lane 0 and lane 32 write their bins
        float* op = out + ((size_t)(b * TU + u)) * M_;
        *(float4*)(op)     = make_float4(p0 + biasc[0], p1 + biasc[1],
                                         p2 + biasc[2], p3 + biasc[3]);
        *(float4*)(op + 4) = make_float4(p4 + biasc[4], p5 + biasc[5],
                                         p6 + biasc[6], p7 + biasc[7]);
    }
}

extern "C" void kernel_launch(void* const* d_in, const int* in_sizes, int n_in,
                              void* d_out, int out_size, void* d_ws, size_t ws_size,
                              hipStream_t stream) {
    const float* x        = (const float*)d_in[0];   // (32,4096,129) f32
    const int*   mask     = (const int*)  d_in[1];   // (32,4096,1) bool->int32
    const float* tw_uniq  = (const float*)d_in[2];   // (32,512,1) f32
    const float* bn_gamma = (const float*)d_in[3];
    const float* bn_beta  = (const float*)d_in[4];
    const float* bn_mean  = (const float*)d_in[5];
    const float* bn_var   = (const float*)d_in[6];
    const float* conv_w   = (const float*)d_in[7];   // (64,128)
    const float* conv_b   = (const float*)d_in[8];   // (64,)
    const float* fc_w     = (const float*)d_in[9];   // (8,64)
    const float* fc_b     = (const float*)d_in[10];  // (8,)
    int*   wsI = (int*)d_ws;                         // ~4.06 MB bins
    float* out = (float*)d_out;                      // (32,512,8) f32

    hipMemsetAsync(wsI, 0, B_ * TU * sizeof(int), stream);   // zero cnt
    fill_kernel<<<256, 512, 0, stream>>>(x, mask, tw_uniq, wsI);
    gather_mm_kernel<<<512, 1024, 0, stream>>>(
        x, bn_gamma, bn_beta, bn_mean, bn_var,
        conv_w, conv_b, fc_w, fc_b, wsI, out);
}